// Round 11
// baseline (172.280 us; speedup 1.0000x reference)
//
#include <hip/hip_runtime.h>
#include <hip/hip_bf16.h>
#include <cstdint>
#include <cstddef>

#define N_ROWS 8192
#define DIM_IN 512
#define MOT 64
#define INV_N2 (1.0f / (8192.0f * 8192.0f))
#define PAIR_BLOCKS 1024   // 4 blocks/CU exactly; 64*9 + 960*8 = 8256 tiles

typedef __attribute__((ext_vector_type(8))) short bf16x8;
typedef __attribute__((ext_vector_type(4))) float f32x4;

#define HALF_L2E 0.721347520444481703f   // 0.5 * log2(e)

__device__ inline float fast_exp2(float x) {
    return __builtin_amdgcn_exp2f(x);    // v_exp_f32, single TRANS inst
}

__device__ inline unsigned short f2bf(float f) {
    union { __hip_bfloat16 h; unsigned short u; } cv;
    cv.h = __float2bfloat16(f);   // RNE
    return cv.u;
}
__device__ inline float bfbits2f(unsigned short u) {
    union { unsigned int i; float f; } cv;
    cv.i = ((unsigned int)u) << 16;
    return cv.f;
}

// ---------------------------------------------------------------------------
// Phase 1 (fused A+B) v4: 1024 blocks x 16 rows (4 blocks/CU resident; R10's
// 512x32 left 2/CU and exposed per-chunk staging latency). Micro-tile c[1][4]:
// a-operand is a 4-way-broadcast scalar LDS read. norms pre-scaled by
// 0.5*log2e; Pbf = bf16(M) in the pair kernel's swizzled tile layout.
// ---------------------------------------------------------------------------
__global__ __launch_bounds__(256) void functor4_kernel(
    const float* __restrict__ XA, const float* __restrict__ WA1, const float* __restrict__ bA1,
    const float* __restrict__ WA2, const float* __restrict__ bA2,
    const float* __restrict__ XB, const float* __restrict__ WB1, const float* __restrict__ bB1,
    const float* __restrict__ WB2, const float* __restrict__ bB2,
    float* __restrict__ MA, float* __restrict__ MB,
    float* __restrict__ nAo, float* __restrict__ nBo,
    unsigned short* __restrict__ PbfA, unsigned short* __restrict__ PbfB)
{
    const int half = blockIdx.x >> 9;          // 0: A path, 1: B path
    const float* X  = half ? XB  : XA;
    const float* W1 = half ? WB1 : WA1;
    const float* b1 = half ? bB1 : bA1;
    const float* W2 = half ? WB2 : WA2;
    const float* b2 = half ? bB2 : bA2;
    float* Mout  = half ? MB  : MA;
    float* norms = half ? nBo : nAo;
    unsigned short* Pbf = half ? PbfB : PbfA;

    __shared__ float XsT[64][17];   // [k][row], 16 rows
    __shared__ float Ws[64][64];
    __shared__ float HsT[64][17];

    const int t  = threadIdx.x;
    const int tx = t & 15;
    const int ty = t >> 4;          // 0..15 = my row
    const int row0 = (blockIdx.x & 511) * 16;

    float c[4] = {0.0f, 0.0f, 0.0f, 0.0f};

    for (int kc = 0; kc < DIM_IN; kc += 64) {
        {   // X: 16 rows x 64 k = 1 float4/thread, transposed store
            int row = t >> 4;
            int k4  = (t & 15) << 2;
            float4 v = *(const float4*)&X[(size_t)(row0 + row) * DIM_IN + kc + k4];
            XsT[k4 + 0][row] = v.x;
            XsT[k4 + 1][row] = v.y;
            XsT[k4 + 2][row] = v.z;
            XsT[k4 + 3][row] = v.w;
        }
        #pragma unroll
        for (int q = 0; q < 4; ++q) {           // W1 chunk: 64x64
            int idx = q * 256 + t;
            int row = idx >> 4;
            int k4  = (idx & 15) << 2;
            *(float4*)&Ws[row][k4] = *(const float4*)&W1[(size_t)(kc + row) * MOT + k4];
        }
        __syncthreads();
        #pragma unroll 8
        for (int k = 0; k < 64; ++k) {
            float a  = XsT[k][ty];
            float4 b = *(const float4*)&Ws[k][tx * 4];
            c[0] = fmaf(a, b.x, c[0]);
            c[1] = fmaf(a, b.y, c[1]);
            c[2] = fmaf(a, b.z, c[2]);
            c[3] = fmaf(a, b.w, c[3]);
        }
        __syncthreads();
    }

    // ---- bias + relu -> HsT (transposed) ----
    {
        float bias1[4];
        #pragma unroll
        for (int j = 0; j < 4; ++j) bias1[j] = b1[tx * 4 + j];
        #pragma unroll
        for (int j = 0; j < 4; ++j) {
            HsT[tx * 4 + j][ty] = fmaxf(c[j] + bias1[j], 0.0f);
            c[j] = 0.0f;
        }
    }

    // ---- stage W2 (L1 compute fully done: loop ended with syncthreads) ----
    #pragma unroll
    for (int q = 0; q < 4; ++q) {
        int idx = q * 256 + t;
        int row = idx >> 4;
        int k4  = (idx & 15) << 2;
        *(float4*)&Ws[row][k4] = *(const float4*)&W2[(size_t)row * MOT + k4];
    }
    __syncthreads();

    // ---- layer 2: K = 64 ----
    #pragma unroll 8
    for (int k = 0; k < 64; ++k) {
        float a  = HsT[k][ty];
        float4 b = *(const float4*)&Ws[k][tx * 4];
        c[0] = fmaf(a, b.x, c[0]);
        c[1] = fmaf(a, b.y, c[1]);
        c[2] = fmaf(a, b.z, c[2]);
        c[3] = fmaf(a, b.w, c[3]);
    }

    // ---- bias + write M + bf16 swizzled copy + norms ----
    float bias2[4];
    #pragma unroll
    for (int j = 0; j < 4; ++j) bias2[j] = b2[tx * 4 + j];

    float p = 0.0f;
    unsigned short q4[4];
    const int grow = row0 + ty;
    #pragma unroll
    for (int j = 0; j < 4; ++j) {
        float m = c[j] + bias2[j];
        Mout[(size_t)grow * MOT + tx * 4 + j] = m;
        q4[j] = f2bf(m);
        float mn = bfbits2f(q4[j]);
        p = fmaf(mn, mn, p);
    }
    {
        int r = grow & 127;
        size_t tile = (size_t)(grow >> 7);
        int swz = (tx * 8) ^ ((r & 7) << 4);
        ushort4 v; v.x = q4[0]; v.y = q4[1]; v.z = q4[2]; v.w = q4[3];
        *(ushort4*)((char*)Pbf + tile * 16384 + (size_t)r * 128 + swz) = v;
    }
    #pragma unroll
    for (int off = 1; off < 16; off <<= 1)
        p += __shfl_xor(p, off, 64);
    if (tx == 0) norms[grow] = HALF_L2E * p;
}

// ---------------------------------------------------------------------------
__device__ inline void decode_tile(int id, int T, int TRI, int& which, int& bi, int& bj) {
    if (id < 2 * TRI) {
        which = (id < TRI) ? 0 : 1;
        if (which) id -= TRI;
        int r = (int)((sqrtf(8.0f * (float)id + 1.0f) - 1.0f) * 0.5f);
        while ((r + 1) * (r + 2) / 2 <= id) ++r;
        while (r * (r + 1) / 2 > id) --r;
        bi = r;
        bj = id - r * (r + 1) / 2;
    } else {
        id -= 2 * TRI;
        which = 2;
        bi = id >> 6;
        bj = id & (T - 1);
    }
}

__device__ inline void step_tile(int& which, int& bi, int& bj, int T) {
    ++bj;
    if (which == 2) {
        if (bj == T) { bj = 0; ++bi; }
    } else {
        if (bj > bi) { bj = 0; ++bi; if (bi == T) { bi = 0; ++which; } }
    }
}

// ---------------------------------------------------------------------------
// Phase 2 v6 (round-9 proven, 42.5us): LDS-free, barrier-free; two 64x32
// passes (acc[4][2] = 32 AGPR) -> 64 arch + 64 acc = exactly 128 regs, 4
// waves/SIMD under launch_bounds(256,4). DO NOT add live state (R10 spilled).
// fminf clamp now unconditional (== reference's maximum(d,0) for all pairs).
// ---------------------------------------------------------------------------
__global__ __launch_bounds__(256, 4) void pair_v6_kernel(
    const unsigned short* __restrict__ PA, const unsigned short* __restrict__ PB,
    const float* __restrict__ nA, const float* __restrict__ nB,
    float* __restrict__ out0)
{
    const int T   = N_ROWS / 128;      // 64
    const int TRI = T * (T + 1) / 2;   // 2080
    const float L2E = 1.44269504088896341f;

    __shared__ float red[4];

    const int t    = threadIdx.x;
    const int lane = t & 63;
    const int wave = t >> 6;
    const int wr   = wave >> 1, wc = wave & 1;
    const int sw   = (lane & 7) << 4;
    const int kb   = (lane >> 4) << 4;

    const int b     = blockIdx.x;
    const int start = (b < 64) ? b * 9 : b * 8 + 64;
    const int len   = (b < 64) ? 9 : 8;

    bf16x8 af[4][2];
    float  nAr[4][4];    // pre-scaled (0.5*log2e) A norms

    auto loadA = [&](int w_, int bi_) {
        const unsigned short* P = (w_ == 1) ? PB : PA;
        const float* nP         = (w_ == 1) ? nB : nA;
        const char* base = (const char*)P + (size_t)bi_ * 16384;
        #pragma unroll
        for (int i = 0; i < 4; ++i) {
            const char* rowp = base + (size_t)(wr * 64 + i * 16 + (lane & 15)) * 128;
            #pragma unroll
            for (int k0 = 0; k0 < 2; ++k0)
                af[i][k0] = *(const bf16x8*)(rowp + ((k0 * 64 + kb) ^ sw));
            float4 n4 = *(const float4*)&nP[bi_ * 128 + wr * 64 + i * 16 + ((lane >> 4) << 2)];
            nAr[i][0] = n4.x; nAr[i][1] = n4.y; nAr[i][2] = n4.z; nAr[i][3] = n4.w;
        }
    };

    int cw, cbi, cbj;
    decode_tile(start, T, TRI, cw, cbi, cbj);
    loadA(cw, cbi);

    float s_acc = 0.0f;

    for (int u = 0; u < len; ++u) {
        const unsigned short* Q = (cw == 0) ? PA : PB;
        const float* nQ         = (cw == 0) ? nA : nB;
        const char* bbase = (const char*)Q + (size_t)cbj * 16384;

        float sa[4] = {0.0f, 0.0f, 0.0f, 0.0f};

        #pragma unroll
        for (int jh = 0; jh < 2; ++jh) {
            // ---- MFMA: A regs x B(L2), 64x32 output ----
            f32x4 acc[4][2] = {};
            #pragma unroll
            for (int k0 = 0; k0 < 2; ++k0) {
                const int koff = (k0 * 64 + kb) ^ sw;
                bf16x8 bfr[2];
                #pragma unroll
                for (int j = 0; j < 2; ++j)
                    bfr[j] = *(const bf16x8*)(bbase +
                        (size_t)(wc * 64 + jh * 32 + j * 16 + (lane & 15)) * 128 + koff);
                #pragma unroll
                for (int i = 0; i < 4; ++i)
                    #pragma unroll
                    for (int j = 0; j < 2; ++j)
                        acc[i][j] = __builtin_amdgcn_mfma_f32_16x16x32_bf16(af[i][k0], bfr[j], acc[i][j], 0, 0, 0);
            }

            float posB[2];
            #pragma unroll
            for (int j = 0; j < 2; ++j)
                posB[j] = nQ[cbj * 128 + wc * 64 + jh * 32 + j * 16 + (lane & 15)];

            // ---- epilogue: exp2(min(dot*log2e - nA' - nB', 0)) ----
            #pragma unroll
            for (int i = 0; i < 4; ++i)
                #pragma unroll
                for (int j = 0; j < 2; ++j)
                    #pragma unroll
                    for (int r = 0; r < 4; ++r) {
                        float tv = fmaf(acc[i][j][r], L2E, -nAr[i][r]) - posB[j];
                        sa[jh * 2 + j] += fast_exp2(fminf(tv, 0.0f));
                    }
        }

        float stile = (sa[0] + sa[1]) + (sa[2] + sa[3]);
        float scale = (cw == 2) ? (-2.0f * INV_N2)
                                : ((cbi != cbj) ? (2.0f * INV_N2) : INV_N2);
        s_acc = fmaf(scale, stile, s_acc);

        if (u + 1 < len) {
            int nw = cw, nbi = cbi, nbj = cbj;
            step_tile(nw, nbi, nbj, T);
            if (nw != cw || nbi != cbi) loadA(nw, nbi);
            cw = nw; cbi = nbi; cbj = nbj;
        }
    }

    #pragma unroll
    for (int off = 32; off > 0; off >>= 1) s_acc += __shfl_xor(s_acc, off, 64);
    if (lane == 0) red[wave] = s_acc;
    __syncthreads();
    if (t == 0) atomicAdd(out0, red[0] + red[1] + red[2] + red[3]);
}

// ---------------------------------------------------------------------------
extern "C" void kernel_launch(void* const* d_in, const int* in_sizes, int n_in,
                              void* d_out, int out_size, void* d_ws, size_t ws_size,
                              hipStream_t stream)
{
    const float* XA  = (const float*)d_in[0];
    const float* XB  = (const float*)d_in[1];
    const float* WA1 = (const float*)d_in[2];
    const float* bA1 = (const float*)d_in[3];
    const float* WA2 = (const float*)d_in[4];
    const float* bA2 = (const float*)d_in[5];
    const float* WB1 = (const float*)d_in[6];
    const float* bB1 = (const float*)d_in[7];
    const float* WB2 = (const float*)d_in[8];
    const float* bB2 = (const float*)d_in[9];

    float* out = (float*)d_out;
    float* MA  = out + 1;
    float* MB  = out + 1 + (size_t)N_ROWS * MOT;
    float* nA  = (float*)d_ws;                           // 8192 f32 (pre-scaled)
    float* nB  = nA + N_ROWS;                            // 8192 f32 (pre-scaled)
    unsigned short* PA = (unsigned short*)(nB + N_ROWS); // 8192x64 bf16 (swizzled)
    unsigned short* PB = PA + (size_t)N_ROWS * MOT;

    hipMemsetAsync(d_out, 0, sizeof(float), stream);     // zero mmd accumulator

    functor4_kernel<<<1024, 256, 0, stream>>>(XA, WA1, bA1, WA2, bA2,
                                              XB, WB1, bB1, WB2, bB2,
                                              MA, MB, nA, nB, PA, PB);

    pair_v6_kernel<<<PAIR_BLOCKS, 256, 0, stream>>>(PA, PB, nA, nB, out);
}

// Round 12
// 99.855 us; speedup vs baseline: 1.7253x; 1.7253x over previous
//
#include <hip/hip_runtime.h>
#include <hip/hip_bf16.h>
#include <cstdint>
#include <cstddef>

#define N_ROWS 8192
#define DIM_IN 512
#define MOT 64
#define INV_N2 (1.0f / (8192.0f * 8192.0f))
#define PAIR_BLOCKS 1024   // 4 blocks/CU exactly; 64*9 + 960*8 = 8256 tiles

typedef __attribute__((ext_vector_type(8))) short bf16x8;
typedef __attribute__((ext_vector_type(4))) float f32x4;

#define HALF_L2E 0.721347520444481703f   // 0.5 * log2(e)

__device__ inline float fast_exp2(float x) {
    return __builtin_amdgcn_exp2f(x);    // v_exp_f32, single TRANS inst
}

__device__ inline unsigned short f2bf(float f) {
    union { __hip_bfloat16 h; unsigned short u; } cv;
    cv.h = __float2bfloat16(f);   // RNE
    return cv.u;
}
__device__ inline float bfbits2f(unsigned short u) {
    union { unsigned int i; float f; } cv;
    cv.i = ((unsigned int)u) << 16;
    return cv.f;
}

// ---------------------------------------------------------------------------
// Phase 1 (fused A+B) v4 (round-11): 1024 blocks x 16 rows. norms pre-scaled
// by 0.5*log2e; Pbf = bf16(M) in the pair kernel's swizzled tile layout.
// ---------------------------------------------------------------------------
__global__ __launch_bounds__(256) void functor4_kernel(
    const float* __restrict__ XA, const float* __restrict__ WA1, const float* __restrict__ bA1,
    const float* __restrict__ WA2, const float* __restrict__ bA2,
    const float* __restrict__ XB, const float* __restrict__ WB1, const float* __restrict__ bB1,
    const float* __restrict__ WB2, const float* __restrict__ bB2,
    float* __restrict__ MA, float* __restrict__ MB,
    float* __restrict__ nAo, float* __restrict__ nBo,
    unsigned short* __restrict__ PbfA, unsigned short* __restrict__ PbfB)
{
    const int half = blockIdx.x >> 9;          // 0: A path, 1: B path
    const float* X  = half ? XB  : XA;
    const float* W1 = half ? WB1 : WA1;
    const float* b1 = half ? bB1 : bA1;
    const float* W2 = half ? WB2 : WA2;
    const float* b2 = half ? bB2 : bA2;
    float* Mout  = half ? MB  : MA;
    float* norms = half ? nBo : nAo;
    unsigned short* Pbf = half ? PbfB : PbfA;

    __shared__ float XsT[64][17];   // [k][row], 16 rows
    __shared__ float Ws[64][64];
    __shared__ float HsT[64][17];

    const int t  = threadIdx.x;
    const int tx = t & 15;
    const int ty = t >> 4;          // 0..15 = my row
    const int row0 = (blockIdx.x & 511) * 16;

    float c[4] = {0.0f, 0.0f, 0.0f, 0.0f};

    for (int kc = 0; kc < DIM_IN; kc += 64) {
        {   // X: 16 rows x 64 k = 1 float4/thread, transposed store
            int row = t >> 4;
            int k4  = (t & 15) << 2;
            float4 v = *(const float4*)&X[(size_t)(row0 + row) * DIM_IN + kc + k4];
            XsT[k4 + 0][row] = v.x;
            XsT[k4 + 1][row] = v.y;
            XsT[k4 + 2][row] = v.z;
            XsT[k4 + 3][row] = v.w;
        }
        #pragma unroll
        for (int q = 0; q < 4; ++q) {           // W1 chunk: 64x64
            int idx = q * 256 + t;
            int row = idx >> 4;
            int k4  = (idx & 15) << 2;
            *(float4*)&Ws[row][k4] = *(const float4*)&W1[(size_t)(kc + row) * MOT + k4];
        }
        __syncthreads();
        #pragma unroll 8
        for (int k = 0; k < 64; ++k) {
            float a  = XsT[k][ty];
            float4 b = *(const float4*)&Ws[k][tx * 4];
            c[0] = fmaf(a, b.x, c[0]);
            c[1] = fmaf(a, b.y, c[1]);
            c[2] = fmaf(a, b.z, c[2]);
            c[3] = fmaf(a, b.w, c[3]);
        }
        __syncthreads();
    }

    {
        float bias1[4];
        #pragma unroll
        for (int j = 0; j < 4; ++j) bias1[j] = b1[tx * 4 + j];
        #pragma unroll
        for (int j = 0; j < 4; ++j) {
            HsT[tx * 4 + j][ty] = fmaxf(c[j] + bias1[j], 0.0f);
            c[j] = 0.0f;
        }
    }

    #pragma unroll
    for (int q = 0; q < 4; ++q) {
        int idx = q * 256 + t;
        int row = idx >> 4;
        int k4  = (idx & 15) << 2;
        *(float4*)&Ws[row][k4] = *(const float4*)&W2[(size_t)row * MOT + k4];
    }
    __syncthreads();

    #pragma unroll 8
    for (int k = 0; k < 64; ++k) {
        float a  = HsT[k][ty];
        float4 b = *(const float4*)&Ws[k][tx * 4];
        c[0] = fmaf(a, b.x, c[0]);
        c[1] = fmaf(a, b.y, c[1]);
        c[2] = fmaf(a, b.z, c[2]);
        c[3] = fmaf(a, b.w, c[3]);
    }

    float bias2[4];
    #pragma unroll
    for (int j = 0; j < 4; ++j) bias2[j] = b2[tx * 4 + j];

    float p = 0.0f;
    unsigned short q4[4];
    const int grow = row0 + ty;
    #pragma unroll
    for (int j = 0; j < 4; ++j) {
        float m = c[j] + bias2[j];
        Mout[(size_t)grow * MOT + tx * 4 + j] = m;
        q4[j] = f2bf(m);
        float mn = bfbits2f(q4[j]);
        p = fmaf(mn, mn, p);
    }
    {
        int r = grow & 127;
        size_t tile = (size_t)(grow >> 7);
        int swz = (tx * 8) ^ ((r & 7) << 4);
        ushort4 v; v.x = q4[0]; v.y = q4[1]; v.z = q4[2]; v.w = q4[3];
        *(ushort4*)((char*)Pbf + tile * 16384 + (size_t)r * 128 + swz) = v;
    }
    #pragma unroll
    for (int off = 1; off < 16; off <<= 1)
        p += __shfl_xor(p, off, 64);
    if (tx == 0) norms[grow] = HALF_L2E * p;
}

// ---------------------------------------------------------------------------
__device__ inline void decode_tile(int id, int T, int TRI, int& which, int& bi, int& bj) {
    if (id < 2 * TRI) {
        which = (id < TRI) ? 0 : 1;
        if (which) id -= TRI;
        int r = (int)((sqrtf(8.0f * (float)id + 1.0f) - 1.0f) * 0.5f);
        while ((r + 1) * (r + 2) / 2 <= id) ++r;
        while (r * (r + 1) / 2 > id) --r;
        bi = r;
        bj = id - r * (r + 1) / 2;
    } else {
        id -= 2 * TRI;
        which = 2;
        bi = id >> 6;
        bj = id & (T - 1);
    }
}

__device__ inline void step_tile(int& which, int& bi, int& bj, int T) {
    ++bj;
    if (which == 2) {
        if (bj == T) { bj = 0; ++bi; }
    } else {
        if (bj > bi) { bj = 0; ++bi; if (bi == T) { bi = 0; ++which; } }
    }
}

// ---------------------------------------------------------------------------
// Phase 2 v8: register-headroom redesign. Wave = 32-ROW band x 128 cols
// (wr = wave id): af[2][2] (16 regs), nAr[2][4] (8), per-pass acc[2][2]
// (16 AGPR). Tile processed as 4 passes of 32 cols; B-frags double-buffered
// (bufE/bufO, 16 regs each) with R10-style prefetch -- now ~100 total regs,
// comfortably under the (256,4) 128 cap (R9 sat at exactly 128; R10/R11
// spilled when scheduling pressure nudged it over).
// ---------------------------------------------------------------------------
__global__ __launch_bounds__(256, 4) void pair_v8_kernel(
    const unsigned short* __restrict__ PA, const unsigned short* __restrict__ PB,
    const float* __restrict__ nA, const float* __restrict__ nB,
    float* __restrict__ out0)
{
    const int T   = N_ROWS / 128;      // 64
    const int TRI = T * (T + 1) / 2;   // 2080
    const float L2E = 1.44269504088896341f;

    __shared__ float red[4];

    const int t     = threadIdx.x;
    const int lane  = t & 63;
    const int wave  = t >> 6;           // row band: rows [wave*32, wave*32+32)
    const int sw    = (lane & 7) << 4;
    const int kb    = (lane >> 4) << 4;
    const int koff0 = kb ^ sw;
    const int koff1 = (64 + kb) ^ sw;
    const int col16 = lane & 15;

    const int b     = blockIdx.x;
    const int start = (b < 64) ? b * 9 : b * 8 + 64;
    const int len   = (b < 64) ? 9 : 8;

    bf16x8 af[2][2];     // A frags: 2 row-blocks x 2 K-halves
    float  nAr[2][4];    // pre-scaled (0.5*log2e) A norms

    auto loadA = [&](int w_, int bi_) {
        const unsigned short* P = (w_ == 1) ? PB : PA;
        const float* nP         = (w_ == 1) ? nB : nA;
        const char* base = (const char*)P + (size_t)bi_ * 16384;
        #pragma unroll
        for (int i = 0; i < 2; ++i) {
            const char* rowp = base + (size_t)(wave * 32 + i * 16 + col16) * 128;
            af[i][0] = *(const bf16x8*)(rowp + koff0);
            af[i][1] = *(const bf16x8*)(rowp + koff1);
            float4 n4 = *(const float4*)&nP[bi_ * 128 + wave * 32 + i * 16 + ((lane >> 4) << 2)];
            nAr[i][0] = n4.x; nAr[i][1] = n4.y; nAr[i][2] = n4.z; nAr[i][3] = n4.w;
        }
    };

    // B quarter: 32 cols (2 x 16) x K64 (2 halves) = 4 frags
    auto loadB4 = [&](bf16x8 (&buf)[4], const char* bb, int jq) {
        #pragma unroll
        for (int j = 0; j < 2; ++j) {
            const char* colp = bb + (size_t)(jq * 32 + j * 16 + col16) * 128;
            buf[j * 2 + 0] = *(const bf16x8*)(colp + koff0);
            buf[j * 2 + 1] = *(const bf16x8*)(colp + koff1);
        }
    };

    int cw, cbi, cbj;
    decode_tile(start, T, TRI, cw, cbi, cbj);
    loadA(cw, cbi);

    const char* bbase;
    const float* nQ;
    {
        const unsigned short* Q = (cw == 0) ? PA : PB;
        nQ    = (cw == 0) ? nA : nB;
        bbase = (const char*)Q + (size_t)cbj * 16384;
    }

    bf16x8 bufE[4], bufO[4];
    loadB4(bufE, bbase, 0);

    float s_acc = 0.0f;

#define PASS(JQ, BCUR, PREFETCH)                                                    \
    {                                                                               \
        f32x4 acc[2][2] = {};                                                       \
        _Pragma("unroll")                                                           \
        for (int k0 = 0; k0 < 2; ++k0)                                              \
            _Pragma("unroll")                                                       \
            for (int i = 0; i < 2; ++i)                                             \
                _Pragma("unroll")                                                   \
                for (int j = 0; j < 2; ++j)                                         \
                    acc[i][j] = __builtin_amdgcn_mfma_f32_16x16x32_bf16(            \
                        af[i][k0], BCUR[j * 2 + k0], acc[i][j], 0, 0, 0);           \
        PREFETCH;                                                                   \
        _Pragma("unroll")                                                           \
        for (int i = 0; i < 2; ++i)                                                 \
            _Pragma("unroll")                                                       \
            for (int j = 0; j < 2; ++j)                                             \
                _Pragma("unroll")                                                   \
                for (int r = 0; r < 4; ++r) {                                       \
                    float tv = fmaf(acc[i][j][r], L2E, -nAr[i][r]) - posB[JQ*2+j];  \
                    sa[JQ] += fast_exp2(fminf(tv, 0.0f));                           \
                }                                                                   \
    }

    for (int u = 0; u < len; ++u) {
        const bool have = (u + 1 < len);
        int nw = cw, nbi = cbi, nbj = cbj;
        if (have) step_tile(nw, nbi, nbj, T);
        const unsigned short* nQp = (nw == 0) ? PA : PB;
        const float* nnQ          = (nw == 0) ? nA : nB;
        const char* nbbase        = (const char*)nQp + (size_t)nbj * 16384;

        // current tile's B norms (8 scalar L2 loads; pass-0 MFMAs cover most latency)
        float posB[8];
        #pragma unroll
        for (int p = 0; p < 8; ++p)
            posB[p] = nQ[cbj * 128 + p * 16 + col16];

        float sa[4] = {0.0f, 0.0f, 0.0f, 0.0f};

        PASS(0, bufE, { loadB4(bufO, bbase, 1); })
        PASS(1, bufO, { loadB4(bufE, bbase, 2); })
        PASS(2, bufE, { loadB4(bufO, bbase, 3); })
        PASS(3, bufO, {
            if (have) {
                loadB4(bufE, nbbase, 0);
                if (nw != cw || nbi != cbi) loadA(nw, nbi);
            }
        })

        float stile = (sa[0] + sa[1]) + (sa[2] + sa[3]);
        float scale = (cw == 2) ? (-2.0f * INV_N2)
                                : ((cbi != cbj) ? (2.0f * INV_N2) : INV_N2);
        s_acc = fmaf(scale, stile, s_acc);

        if (have) {
            cw = nw; cbi = nbi; cbj = nbj;
            bbase = nbbase; nQ = nnQ;
        }
    }
#undef PASS

    #pragma unroll
    for (int off = 32; off > 0; off >>= 1) s_acc += __shfl_xor(s_acc, off, 64);
    if (lane == 0) red[wave] = s_acc;
    __syncthreads();
    if (t == 0) atomicAdd(out0, red[0] + red[1] + red[2] + red[3]);
}

// ---------------------------------------------------------------------------
extern "C" void kernel_launch(void* const* d_in, const int* in_sizes, int n_in,
                              void* d_out, int out_size, void* d_ws, size_t ws_size,
                              hipStream_t stream)
{
    const float* XA  = (const float*)d_in[0];
    const float* XB  = (const float*)d_in[1];
    const float* WA1 = (const float*)d_in[2];
    const float* bA1 = (const float*)d_in[3];
    const float* WA2 = (const float*)d_in[4];
    const float* bA2 = (const float*)d_in[5];
    const float* WB1 = (const float*)d_in[6];
    const float* bB1 = (const float*)d_in[7];
    const float* WB2 = (const float*)d_in[8];
    const float* bB2 = (const float*)d_in[9];

    float* out = (float*)d_out;
    float* MA  = out + 1;
    float* MB  = out + 1 + (size_t)N_ROWS * MOT;
    float* nA  = (float*)d_ws;                           // 8192 f32 (pre-scaled)
    float* nB  = nA + N_ROWS;                            // 8192 f32 (pre-scaled)
    unsigned short* PA = (unsigned short*)(nB + N_ROWS); // 8192x64 bf16 (swizzled)
    unsigned short* PB = PA + (size_t)N_ROWS * MOT;

    hipMemsetAsync(d_out, 0, sizeof(float), stream);     // zero mmd accumulator

    functor4_kernel<<<1024, 256, 0, stream>>>(XA, WA1, bA1, WA2, bA2,
                                              XB, WB1, bB1, WB2, bB2,
                                              MA, MB, nA, nB, PA, PB);

    pair_v8_kernel<<<PAIR_BLOCKS, 256, 0, stream>>>(PA, PB, nA, nB, out);
}